// Round 1
// baseline (314.506 us; speedup 1.0000x reference)
//
#include <hip/hip_runtime.h>
#include <math.h>

// GroupedQueryAttention: B=4,S=128,D=4096,H=32,KV=8,HD=128,REP=4
// Round 7: kill split-K HBM partials. K is split across 2 wave-groups
// INSIDE each gemm block (512 thr), reduced through LDS, with the
// bias+RoPE+fp16-repack epilogue fused into the gemm. Deletes
// qkv_reduce_rope + o_reduce (+~167 MB HBM round trip). wo-transpose
// rides in the attention launch (idle BW there); WtO aliases Wt.

#define B_   4
#define S_   128
#define D_   4096
#define H_   32
#define KV_  8
#define HD_  128
#define M_   (B_ * S_)        // 512 rows
#define NQKV 6144
#define SCALE_ 0.088388347648318447f  // 1/sqrt(128)

typedef _Float16 half_t;
typedef half_t f16x8 __attribute__((ext_vector_type(8)));
typedef float  f32x4 __attribute__((ext_vector_type(4)));

__device__ inline void load_lds16(const void* g, void* l) {
    __builtin_amdgcn_global_load_lds((const __attribute__((address_space(1))) void*)g,
                                     (__attribute__((address_space(3))) void*)l,
                                     16, 0, 0);
}

// ---------------------------------------------------------------------------
// One 128n x 64k transpose tile: W[k0..+64][nsrc0..+128] fp32 ->
// Wt slab (k0/64): rows ndst0..+128 x 64 halfs  (16KB contiguous write).
// 256 threads.
__device__ void transpose_tile(const float* __restrict__ src, int Nsrc, int nsrc0,
                               int ndst0, int k0, int Ntot,
                               half_t* __restrict__ Wt, void* ldsraw) {
    float (*tile)[132] = (float(*)[132])ldsraw;   // [64k][128n], pad 132
    const int t = threadIdx.x;
#pragma unroll
    for (int p = 0; p < 8; ++p) {
        int idx = t + p * 256;              // 2048 float4 tasks
        int r = idx >> 5, c4 = idx & 31;    // 64 k-rows x 32 float4
        *(float4*)&tile[r][c4 * 4] =
            *(const float4*)&src[(size_t)(k0 + r) * Nsrc + nsrc0 + c4 * 4];
    }
    __syncthreads();
    const int n = t >> 1, kh = t & 1;       // 128 n-rows, 2 k-halves of 32
    __align__(16) half_t hs[32];
#pragma unroll
    for (int i = 0; i < 32; ++i)
        hs[i] = (half_t)tile[kh * 32 + i][n];
    size_t ob = ((size_t)(k0 >> 6) * Ntot + ndst0 + n) * 64 + kh * 32;
#pragma unroll
    for (int u = 0; u < 4; ++u)
        *(uint4*)&Wt[ob + u * 8] = *(uint4*)&hs[u * 8];
}

// ---------------------------------------------------------------------------
// Packed: QKV weight transpose (3072 blocks) + x fp32->fp16 (512 blocks).
__global__ __launch_bounds__(256)
void prep_qkv(const float* __restrict__ wq, const float* __restrict__ wk,
              const float* __restrict__ wv, const float* __restrict__ x,
              half_t* __restrict__ Wt, half_t* __restrict__ x16) {
    __shared__ __align__(16) char lds[33792];
    const int bx = blockIdx.x;
    if (bx < 3072) {
        int nt = bx % 48, kt = bx / 48;
        const float* src; int Nsrc, ns0, nd0;
        if (nt < 32)      { src = wq; Nsrc = 4096; ns0 = nt * 128;        nd0 = nt * 128; }
        else if (nt < 40) { src = wk; Nsrc = 1024; ns0 = (nt - 32) * 128; nd0 = 4096 + (nt - 32) * 128; }
        else              { src = wv; Nsrc = 1024; ns0 = (nt - 40) * 128; nd0 = 5120 + (nt - 40) * 128; }
        transpose_tile(src, Nsrc, ns0, nd0, kt * 64, NQKV, Wt, lds);
    } else {
        int i0 = (bx - 3072) * 1024 + threadIdx.x;
#pragma unroll
        for (int j = 0; j < 4; ++j) {
            int i = i0 + j * 256;
            float4 f = ((const float4*)x)[i];
            __align__(8) half_t h4[4] = {(half_t)f.x, (half_t)f.y, (half_t)f.z, (half_t)f.w};
            ((uint2*)x16)[i] = *(uint2*)h4;
        }
    }
}

// ---------------------------------------------------------------------------
// QKV gemm, full K=4096 per block. 512 threads = 2 K-groups x 4 waves.
// Each group: 128x128 tile, BK=64, own 32KB LDS staging, lockstep barriers.
// End: group1 acc -> LDS, group0 adds, fused bias+RoPE epilogue writes
// q16 [512][4096], k16 [512][1024], vt16 [B*KV][128d][128i] (fp16).
// Grid 192 = 48 n-tiles x 4 m-tiles.
__global__ __launch_bounds__(512)
void gemm_qkv_fused(const half_t* __restrict__ x16, const half_t* __restrict__ Wt,
                    const float* __restrict__ bq, const float* __restrict__ bk,
                    const float* __restrict__ bv, const float* __restrict__ fc,
                    const float* __restrict__ fs, half_t* __restrict__ q16,
                    half_t* __restrict__ k16, half_t* __restrict__ vt16) {
    __shared__ __align__(16) char lds[67584];   // 64KB staging | [128][132] f32 reduce
    const int tid = threadIdx.x;
    const int nb = blockIdx.x % 48, mb = blockIdx.x / 48;
    const int m0 = mb * 128, n0 = nb * 128;
    const int g = tid >> 8;                 // K-group (waves 0-3 / 4-7)
    const int lane = tid & 63;
    const int quad = lane >> 4, l16 = lane & 15;
    const int w4 = (tid >> 6) & 3;          // wave within group
    const int wm = (w4 & 1) * 64, wn = (w4 >> 1) * 64;
    const int tB = tid & 192;               // wave-uniform base within group

    half_t (*As)[64] = (half_t(*)[64])(lds + g * 32768);
    half_t (*Bs)[64] = (half_t(*)[64])(lds + g * 32768 + 16384);

    f32x4 acc[4][4] = {};
    const int kend = g * 2048 + 2048;
    for (int kc = g * 2048; kc < kend; kc += 64) {
        const half_t* Bslab = Wt + ((size_t)(kc >> 6) * NQKV + n0) * 64;
#pragma unroll
        for (int p = 0; p < 4; ++p) {
            int tb = p * 256 + tB;          // wave-uniform
            int task = tb + lane;
            int r = task >> 3;
            int os = (task ^ r) & 7;        // XOR swizzle within 64-half row
            load_lds16(&x16[(size_t)(m0 + r) * 4096 + kc + os * 8], (half_t*)As + tb * 8);
            load_lds16(&Bslab[(size_t)r * 64 + os * 8],             (half_t*)Bs + tb * 8);
        }
        __syncthreads();
#pragma unroll
        for (int kk = 0; kk < 2; ++kk) {
            f16x8 af[4], bf[4];
#pragma unroll
            for (int i = 0; i < 4; ++i) {
                int ra = wm + i * 16 + l16;
                int rb = wn + i * 16 + l16;
                int L = kk * 4 + quad;
                af[i] = *(const f16x8*)&As[ra][(L ^ (ra & 7)) * 8];
                bf[i] = *(const f16x8*)&Bs[rb][(L ^ (rb & 7)) * 8];
            }
#pragma unroll
            for (int i = 0; i < 4; ++i)
#pragma unroll
                for (int j = 0; j < 4; ++j)
                    acc[i][j] = __builtin_amdgcn_mfma_f32_16x16x32_f16(af[i], bf[j], acc[i][j], 0, 0, 0);
        }
        __syncthreads();
    }

    // cross-group K reduce through LDS
    float (*Tf)[132] = (float(*)[132])lds;
    if (g == 1) {
#pragma unroll
        for (int i = 0; i < 4; ++i)
#pragma unroll
            for (int j = 0; j < 4; ++j)
#pragma unroll
                for (int rg = 0; rg < 4; ++rg)
                    Tf[wm + i * 16 + quad * 4 + rg][wn + j * 16 + l16] = acc[i][j][rg];
    }
    __syncthreads();
    if (g == 0) {
#pragma unroll
        for (int i = 0; i < 4; ++i)
#pragma unroll
            for (int j = 0; j < 4; ++j)
#pragma unroll
                for (int rg = 0; rg < 4; ++rg)
                    acc[i][j][rg] += Tf[wm + i * 16 + quad * 4 + rg][wn + j * 16 + l16];
    }

    if (n0 < 5120) {
        // Q or K tile: bias + RoPE (adjacent-lane pairs) + fp16 store, group0 only
        if (g == 0) {
            const bool isQ = n0 < 4096;
            const float* bias = isQ ? bq : bk;
            const int bOff = isQ ? 0 : 4096;
            half_t* dst = isQ ? q16 : k16;
            const int ldd = isQ ? 4096 : 1024;
#pragma unroll
            for (int i = 0; i < 4; ++i)
#pragma unroll
                for (int j = 0; j < 4; ++j) {
                    const int col = n0 + wn + j * 16 + l16;     // even iff l16 even
                    const int d2 = (col >> 1) & 63;
                    const float bcol = bias[col - bOff];
#pragma unroll
                    for (int rg = 0; rg < 4; ++rg) {
                        const int row = m0 + wm + i * 16 + quad * 4 + rg;
                        float v = acc[i][j][rg] + bcol;
                        float o = __shfl_xor(v, 1);             // partner of (re,im) pair
                        const int iloc = row & 127;
                        const float c = fc[iloc * 64 + d2], sn = fs[iloc * 64 + d2];
                        float ov = (l16 & 1) ? (o * sn + v * c)   // im' = re*s + im*c
                                             : (v * c - o * sn);  // re' = re*c - im*s
                        float o2 = __shfl_xor(ov, 1);
                        if (!(l16 & 1)) {
                            __align__(4) half_t hh[2] = {(half_t)ov, (half_t)o2};
                            *(unsigned int*)&dst[(size_t)row * ldd + (col - bOff)] =
                                *(unsigned int*)hh;
                        }
                    }
                }
        }
    } else {
        // V tile: bias -> LDS fp16 -> transposed coalesced store to vt16[d][i]
        __syncthreads();                    // Tf reads done before overwrite
        half_t (*Th)[136] = (half_t(*)[136])lds;
        if (g == 0) {
#pragma unroll
            for (int i = 0; i < 4; ++i)
#pragma unroll
                for (int j = 0; j < 4; ++j) {
                    const int cl = wn + j * 16 + l16;
                    const float bcol = bv[n0 - 5120 + cl];
#pragma unroll
                    for (int rg = 0; rg < 4; ++rg)
                        Th[wm + i * 16 + quad * 4 + rg][cl] = (half_t)(acc[i][j][rg] + bcol);
                }
        }
        __syncthreads();
        const int d = tid >> 2, iq = tid & 3;       // 128 d x 4 i-quarters
        const int kv = (n0 - 5120) >> 7;
        __align__(16) half_t hs[32];
#pragma unroll
        for (int u = 0; u < 32; ++u) hs[u] = Th[iq * 32 + u][d];
        size_t base = ((size_t)(mb * 8 + kv) * 128 + d) * 128 + iq * 32;
#pragma unroll
        for (int u = 0; u < 4; ++u)
            *(uint4*)&vt16[base + u * 8] = *(uint4*)&hs[u * 8];
    }
}

// ---------------------------------------------------------------------------
// Packed: fused attention (512 blocks) + wo transpose (2048 blocks).
// wo-T output WtO aliases Wt (safe: Wt last read in previous launch).
__global__ __launch_bounds__(256, 2)
void attn_wo(const half_t* __restrict__ q16, const half_t* __restrict__ k16,
             const half_t* __restrict__ vt16, half_t* __restrict__ a16,
             const float* __restrict__ wo, half_t* __restrict__ WtO) {
    __shared__ __align__(16) char lds[62464];
    if (blockIdx.x >= 512) {
        int t = blockIdx.x - 512;
        transpose_tile(wo, 4096, (t & 31) * 128, (t & 31) * 128, (t >> 5) * 64,
                       4096, WtO, lds);
        return;
    }
    half_t (*Qs)[136] = (half_t(*)[136])lds;            //  8704 B
    half_t (*Ks)[136] = (half_t(*)[136])(lds + 8704);   // 34816 B
    float (*Ps)[132]  = (float(*)[132])(lds + 43520);   // 16896 B
    float (*red)[16]  = (float(*)[16])(lds + 60416);    //  2048 B

    const int tid = threadIdx.x;
    const int qi = blockIdx.x & 3, h = (blockIdx.x >> 2) & 31, b = blockIdx.x >> 7;
    const int kv = h >> 2;
    const int qbase = qi * 32;
    const int lane = tid & 63, w = tid >> 6;
    const int quad = lane >> 4, l16 = lane & 15;
    const int m0 = (w & 1) * 16, half64 = (w >> 1) * 64;

#pragma unroll
    for (int p = 0; p < 2; ++p) {
        int task = tid + p * 256;
        int r = task >> 4, c = task & 15;
        *(uint4*)&Qs[r][c * 8] =
            *(const uint4*)&q16[((size_t)(b * 128 + qbase + r) * 32 + h) * 128 + c * 8];
    }
#pragma unroll
    for (int p = 0; p < 8; ++p) {
        int task = tid + p * 256;
        int r = task >> 4, c = task & 15;
        *(uint4*)&Ks[r][c * 8] =
            *(const uint4*)&k16[((size_t)(b * 128 + r) * 8 + kv) * 128 + c * 8];
    }
    __syncthreads();

    // phase 1: S = Q K^T
    f32x4 s[4] = {};
#pragma unroll
    for (int kc = 0; kc < 4; ++kc) {
        f16x8 af = *(const f16x8*)&Qs[m0 + l16][kc * 32 + quad * 8];
#pragma unroll
        for (int jb = 0; jb < 4; ++jb) {
            f16x8 bf = *(const f16x8*)&Ks[half64 + jb * 16 + l16][kc * 32 + quad * 8];
            s[jb] = __builtin_amdgcn_mfma_f32_16x16x32_f16(af, bf, s[jb], 0, 0, 0);
        }
    }
#pragma unroll
    for (int jb = 0; jb < 4; ++jb) {
        int j = half64 + jb * 16 + l16;
#pragma unroll
        for (int rg = 0; rg < 4; ++rg) {
            int row = m0 + quad * 4 + rg;
            Ps[row][j] = (j <= qbase + row) ? s[jb][rg] * SCALE_ : -1e30f;
        }
    }
    __syncthreads();

    // softmax: thread t -> row r, 16-col segment seg
    const int r = tid >> 3, seg = tid & 7;
    float mx = -1e30f;
#pragma unroll
    for (int i = 0; i < 16; ++i) mx = fmaxf(mx, Ps[r][seg * 16 + i]);
    red[r][seg] = mx;
    __syncthreads();

    uint4 vstage[8];
#pragma unroll
    for (int p = 0; p < 8; ++p) {
        int task = tid + p * 256;
        int rr = task >> 4, c = task & 15;
        vstage[p] = *(const uint4*)&vt16[((size_t)(b * 8 + kv) * 128 + rr) * 128 + c * 8];
    }
    float m = red[r][0];
#pragma unroll
    for (int i = 1; i < 8; ++i) m = fmaxf(m, red[r][i]);
    float sum = 0.f;
#pragma unroll
    for (int i = 0; i < 16; ++i) {
        float e = __expf(Ps[r][seg * 16 + i] - m);
        Ps[r][seg * 16 + i] = e;
        sum += e;
    }
    red[r][8 + seg] = sum;
#pragma unroll
    for (int p = 0; p < 8; ++p) {
        int task = tid + p * 256;
        int rr = task >> 4, c = task & 15;
        *(uint4*)&Ks[rr][c * 8] = vstage[p];   // Vt[d][j]
    }
    __syncthreads();

    float tot = 0.f;
#pragma unroll
    for (int i = 0; i < 8; ++i) tot += red[r][8 + i];
    float inv = 1.0f / tot;
#pragma unroll
    for (int i = 0; i < 16; ++i)
        Qs[r][seg * 16 + i] = (half_t)(Ps[r][seg * 16 + i] * inv);
    __syncthreads();

    // phase 2: O = P V
    f32x4 o[4] = {};
#pragma unroll
    for (int jc = 0; jc < 4; ++jc) {
        f16x8 af = *(const f16x8*)&Qs[m0 + l16][jc * 32 + quad * 8];
#pragma unroll
        for (int db = 0; db < 4; ++db) {
            f16x8 bf = *(const f16x8*)&Ks[half64 + db * 16 + l16][jc * 32 + quad * 8];
            o[db] = __builtin_amdgcn_mfma_f32_16x16x32_f16(af, bf, o[db], 0, 0, 0);
        }
    }
#pragma unroll
    for (int db = 0; db < 4; ++db) {
        int d = half64 + db * 16 + l16;
#pragma unroll
        for (int rg = 0; rg < 4; ++rg) {
            int row = m0 + quad * 4 + rg;
            a16[(size_t)(b * 128 + qbase + row) * 4096 + h * 128 + d] = (half_t)o[db][rg];
        }
    }
}

// ---------------------------------------------------------------------------
// O projection, full K=4096, fused +bo, fp32 store. BM=64 x BN=128.
// 512 threads = 2 K-groups x 4 waves (each wave 64m x 32n, acc[4][2]).
// Grid 256 = 8 m-tiles x 32 n-tiles.
__global__ __launch_bounds__(512)
void gemm_o_fused(const half_t* __restrict__ a16, const half_t* __restrict__ WtO,
                  const float* __restrict__ bo, float* __restrict__ out) {
    __shared__ __align__(16) char lds[49152];   // 2 x (8KB A + 16KB B) | [64][132] f32
    const int tid = threadIdx.x;
    const int nb = blockIdx.x & 31, mb = blockIdx.x >> 5;
    const int m0 = mb * 64, n0 = nb * 128;
    const int g = tid >> 8;
    const int lane = tid & 63;
    const int quad = lane >> 4, l16 = lane & 15;
    const int w4 = (tid >> 6) & 3;
    const int wn = w4 * 32;
    const int tB = tid & 192;

    half_t (*As)[64] = (half_t(*)[64])(lds + g * 24576);
    half_t (*Bs)[64] = (half_t(*)[64])(lds + g * 24576 + 8192);

    f32x4 acc[4][2] = {};
    const int kend = g * 2048 + 2048;
    for (int kc = g * 2048; kc < kend; kc += 64) {
        const half_t* Bslab = WtO + ((size_t)(kc >> 6) * 4096 + n0) * 64;
#pragma unroll
        for (int p = 0; p < 4; ++p) {
            int tb = p * 256 + tB;
            int task = tb + lane;
            int r = task >> 3;
            int os = (task ^ r) & 7;
            load_lds16(&Bslab[(size_t)r * 64 + os * 8], (half_t*)Bs + tb * 8);
            if (p < 2)      // A: 64 rows -> 512 tasks
                load_lds16(&a16[(size_t)(m0 + r) * 4096 + kc + os * 8], (half_t*)As + tb * 8);
        }
        __syncthreads();
#pragma unroll
        for (int kk = 0; kk < 2; ++kk) {
            f16x8 af[4], bf[2];
#pragma unroll
            for (int i = 0; i < 4; ++i) {
                int ra = i * 16 + l16;
                af[i] = *(const f16x8*)&As[ra][((kk * 4 + quad) ^ (ra & 7)) * 8];
            }
#pragma unroll
            for (int j = 0; j < 2; ++j) {
                int rb = wn + j * 16 + l16;
                bf[j] = *(const f16x8*)&Bs[rb][((kk * 4 + quad) ^ (rb & 7)) * 8];
            }
#pragma unroll
            for (int i = 0; i < 4; ++i)
#pragma unroll
                for (int j = 0; j < 2; ++j)
                    acc[i][j] = __builtin_amdgcn_mfma_f32_16x16x32_f16(af[i], bf[j], acc[i][j], 0, 0, 0);
        }
        __syncthreads();
    }

    float (*Tf)[132] = (float(*)[132])lds;      // 64x132x4 = 33792 B
    if (g == 1) {
#pragma unroll
        for (int i = 0; i < 4; ++i)
#pragma unroll
            for (int j = 0; j < 2; ++j)
#pragma unroll
                for (int rg = 0; rg < 4; ++rg)
                    Tf[i * 16 + quad * 4 + rg][wn + j * 16 + l16] = acc[i][j][rg];
    }
    __syncthreads();
    if (g == 0) {
#pragma unroll
        for (int i = 0; i < 4; ++i)
#pragma unroll
            for (int j = 0; j < 2; ++j) {
                const int col = n0 + wn + j * 16 + l16;
                const float bcol = bo[col];
#pragma unroll
                for (int rg = 0; rg < 4; ++rg) {
                    const int row = m0 + i * 16 + quad * 4 + rg;
                    out[(size_t)row * 4096 + col] =
                        acc[i][j][rg] + Tf[i * 16 + quad * 4 + rg][wn + j * 16 + l16] + bcol;
                }
            }
    }
}

// ---------------------------------------------------------------------------
extern "C" void kernel_launch(void* const* d_in, const int* in_sizes, int n_in,
                              void* d_out, int out_size, void* d_ws, size_t ws_size,
                              hipStream_t stream) {
    const float* x    = (const float*)d_in[0];
    const float* fc   = (const float*)d_in[2];
    const float* fs   = (const float*)d_in[3];
    const float* wq   = (const float*)d_in[7];
    const float* bq   = (const float*)d_in[8];
    const float* wk   = (const float*)d_in[9];
    const float* bk   = (const float*)d_in[10];
    const float* wv   = (const float*)d_in[11];
    const float* bv   = (const float*)d_in[12];
    const float* wo   = (const float*)d_in[13];
    const float* bo   = (const float*)d_in[14];
    float* out = (float*)d_out;

    half_t* x16  = (half_t*)d_ws;            //  2,097,152 h
    half_t* a16  = x16 + 2097152;            //  2,097,152 h
    half_t* q16  = a16 + 2097152;            //  2,097,152 h
    half_t* k16  = q16 + 2097152;            //    524,288 h
    half_t* vt16 = k16 + 524288;             //    524,288 h
    half_t* Wt   = vt16 + 524288;            // 25,165,824 h (ends @65,011,712 B)
    half_t* WtO  = Wt;                       // alias: wo-T runs after QKV gemm,
                                             // which is the last reader of Wt.

    // 1. QKV weight transpose + x convert
    prep_qkv<<<3584, 256, 0, stream>>>(wq, wk, wv, x, Wt, x16);

    // 2. QKV gemm, full-K, in-block K-split, fused bias+RoPE epilogue
    gemm_qkv_fused<<<192, 512, 0, stream>>>(x16, Wt, bq, bk, bv, fc, fs,
                                            q16, k16, vt16);

    // 3. fused attention + wo transpose packed into idle BW
    attn_wo<<<2560, 256, 0, stream>>>(q16, k16, vt16, a16, wo, WtO);

    // 4. O projection, full-K, fused +bo, direct fp32 out
    gemm_o_fused<<<256, 512, 0, stream>>>(a16, WtO, bo, out);
}

// Round 2
// 301.505 us; speedup vs baseline: 1.0431x; 1.0431x over previous
//
#include <hip/hip_runtime.h>
#include <math.h>

// GroupedQueryAttention: B=4,S=128,D=4096,H=32,KV=8,HD=128,REP=4
// Round 8: fix round-7's latency-bound gemm (occupancy 13%, MfmaUtil 12%).
//   - 64x128 full-K tiles: QKV grid 384, O grid 256 (was 192/256 @ 512thr)
//   - double-buffered global_load_lds prefetch, ONE barrier per BK=64 step
//   - bijective XCD swizzle so same-n blocks share a B-slab in one L2
//   Fused epilogues (bias+RoPE+fp16 / V-transpose / +bo) kept from r7.

#define B_   4
#define S_   128
#define D_   4096
#define H_   32
#define KV_  8
#define HD_  128
#define M_   (B_ * S_)        // 512 rows
#define NQKV 6144
#define SCALE_ 0.088388347648318447f  // 1/sqrt(128)

typedef _Float16 half_t;
typedef half_t f16x8 __attribute__((ext_vector_type(8)));
typedef float  f32x4 __attribute__((ext_vector_type(4)));

__device__ inline void load_lds16(const void* g, void* l) {
    __builtin_amdgcn_global_load_lds((const __attribute__((address_space(1))) void*)g,
                                     (__attribute__((address_space(3))) void*)l,
                                     16, 0, 0);
}

// ---------------------------------------------------------------------------
// One 128n x 64k transpose tile: W[k0..+64][nsrc0..+128] fp32 ->
// Wt slab (k0/64): rows ndst0..+128 x 64 halfs  (16KB contiguous write).
// 256 threads.
__device__ void transpose_tile(const float* __restrict__ src, int Nsrc, int nsrc0,
                               int ndst0, int k0, int Ntot,
                               half_t* __restrict__ Wt, void* ldsraw) {
    float (*tile)[132] = (float(*)[132])ldsraw;   // [64k][128n], pad 132
    const int t = threadIdx.x;
#pragma unroll
    for (int p = 0; p < 8; ++p) {
        int idx = t + p * 256;              // 2048 float4 tasks
        int r = idx >> 5, c4 = idx & 31;    // 64 k-rows x 32 float4
        *(float4*)&tile[r][c4 * 4] =
            *(const float4*)&src[(size_t)(k0 + r) * Nsrc + nsrc0 + c4 * 4];
    }
    __syncthreads();
    const int n = t >> 1, kh = t & 1;       // 128 n-rows, 2 k-halves of 32
    __align__(16) half_t hs[32];
#pragma unroll
    for (int i = 0; i < 32; ++i)
        hs[i] = (half_t)tile[kh * 32 + i][n];
    size_t ob = ((size_t)(k0 >> 6) * Ntot + ndst0 + n) * 64 + kh * 32;
#pragma unroll
    for (int u = 0; u < 4; ++u)
        *(uint4*)&Wt[ob + u * 8] = *(uint4*)&hs[u * 8];
}

// ---------------------------------------------------------------------------
// Packed: QKV weight transpose (3072 blocks) + x fp32->fp16 (512 blocks).
__global__ __launch_bounds__(256)
void prep_qkv(const float* __restrict__ wq, const float* __restrict__ wk,
              const float* __restrict__ wv, const float* __restrict__ x,
              half_t* __restrict__ Wt, half_t* __restrict__ x16) {
    __shared__ __align__(16) char lds[33792];
    const int bx = blockIdx.x;
    if (bx < 3072) {
        int nt = bx % 48, kt = bx / 48;
        const float* src; int Nsrc, ns0, nd0;
        if (nt < 32)      { src = wq; Nsrc = 4096; ns0 = nt * 128;        nd0 = nt * 128; }
        else if (nt < 40) { src = wk; Nsrc = 1024; ns0 = (nt - 32) * 128; nd0 = 4096 + (nt - 32) * 128; }
        else              { src = wv; Nsrc = 1024; ns0 = (nt - 40) * 128; nd0 = 5120 + (nt - 40) * 128; }
        transpose_tile(src, Nsrc, ns0, nd0, kt * 64, NQKV, Wt, lds);
    } else {
        int i0 = (bx - 3072) * 1024 + threadIdx.x;
#pragma unroll
        for (int j = 0; j < 4; ++j) {
            int i = i0 + j * 256;
            float4 f = ((const float4*)x)[i];
            __align__(8) half_t h4[4] = {(half_t)f.x, (half_t)f.y, (half_t)f.z, (half_t)f.w};
            ((uint2*)x16)[i] = *(uint2*)h4;
        }
    }
}

// ---------------------------------------------------------------------------
// 64m x 128n full-K=4096 gemm core, 256 threads (4 waves, each 64m x 32n).
// Double-buffered LDS: As[2][64][64] @0 (16KB), Bs[2][128][64] @16KB (32KB).
// Prefetch tile t+1 via global_load_lds before computing tile t; one barrier
// per BK=64 step (its vmcnt(0) drain completes the prefetch).
__device__ __forceinline__ void stage64x128(const half_t* __restrict__ A,
                                            const half_t* __restrict__ Bbase,
                                            int N, int m0, int n0, int kc,
                                            half_t* AsD, half_t* BsD, int tid) {
    const int lane = tid & 63, tB = tid & 192;
    const half_t* Bslab = Bbase + ((size_t)(kc >> 6) * N + n0) * 64;
#pragma unroll
    for (int p = 0; p < 2; ++p) {           // A: 512 tasks (64 rows x 8 chunks)
        int tb = p * 256 + tB;
        int task = tb + lane;
        int r = task >> 3, os = (task ^ r) & 7;
        load_lds16(&A[(size_t)(m0 + r) * 4096 + kc + os * 8], AsD + tb * 8);
    }
#pragma unroll
    for (int p = 0; p < 4; ++p) {           // B: 1024 tasks (128 rows x 8 chunks)
        int tb = p * 256 + tB;
        int task = tb + lane;
        int r = task >> 3, os = (task ^ r) & 7;
        load_lds16(&Bslab[(size_t)r * 64 + os * 8], BsD + tb * 8);
    }
}

__device__ __forceinline__ void compute64x128(const half_t* AsD, const half_t* BsD,
                                              int tid, f32x4 (&acc)[4][2]) {
    const int lane = tid & 63;
    const int quad = lane >> 4, l16 = lane & 15;
    const int wn = (tid >> 6) * 32;
    half_t (*As)[64] = (half_t(*)[64])AsD;
    half_t (*Bs)[64] = (half_t(*)[64])BsD;
#pragma unroll
    for (int kk = 0; kk < 2; ++kk) {
        f16x8 af[4], bf[2];
        int L = kk * 4 + quad;
#pragma unroll
        for (int i = 0; i < 4; ++i) {
            int ra = i * 16 + l16;
            af[i] = *(const f16x8*)&As[ra][(L ^ (ra & 7)) * 8];
        }
#pragma unroll
        for (int j = 0; j < 2; ++j) {
            int rb = wn + j * 16 + l16;
            bf[j] = *(const f16x8*)&Bs[rb][(L ^ (rb & 7)) * 8];
        }
#pragma unroll
        for (int i = 0; i < 4; ++i)
#pragma unroll
            for (int j = 0; j < 2; ++j)
                acc[i][j] = __builtin_amdgcn_mfma_f32_16x16x32_f16(af[i], bf[j], acc[i][j], 0, 0, 0);
    }
}

__device__ __forceinline__ void gemm64x128(const half_t* __restrict__ A,
                                           const half_t* __restrict__ Bbase,
                                           int N, int m0, int n0, char* lds,
                                           f32x4 (&acc)[4][2]) {
    const int tid = threadIdx.x;
    half_t* As0 = (half_t*)lds;              // [2][64][64]
    half_t* Bs0 = (half_t*)(lds + 16384);    // [2][128][64]
    stage64x128(A, Bbase, N, m0, n0, 0, As0, Bs0, tid);
    __syncthreads();
    int cur = 0;
    for (int it = 0; it < 63; ++it) {
        int nxt = cur ^ 1;
        stage64x128(A, Bbase, N, m0, n0, (it + 1) * 64,
                    As0 + nxt * 4096, Bs0 + nxt * 8192, tid);
        compute64x128(As0 + cur * 4096, Bs0 + cur * 8192, tid, acc);
        __syncthreads();                     // drains prefetch (vmcnt 0)
        cur = nxt;
    }
    compute64x128(As0 + cur * 4096, Bs0 + cur * 8192, tid, acc);
    __syncthreads();                         // LDS free for epilogue reuse
}

// ---------------------------------------------------------------------------
// QKV gemm + fused bias+RoPE+fp16 epilogue.
// Grid 384 = 8 m-tiles x 48 n-tiles, XCD-swizzled (same-n blocks -> same XCD).
__global__ __launch_bounds__(256, 2)
void gemm_qkv_fused(const half_t* __restrict__ x16, const half_t* __restrict__ Wt,
                    const float* __restrict__ bq, const float* __restrict__ bk,
                    const float* __restrict__ bv, const float* __restrict__ fc,
                    const float* __restrict__ fs, half_t* __restrict__ q16,
                    half_t* __restrict__ k16, half_t* __restrict__ vt16) {
    __shared__ __align__(16) char lds[49152];
    const int bx = blockIdx.x;
    const int o = (bx & 7) * 48 + (bx >> 3);  // bijective, 384 = 8 XCD x 48
    const int nb = o >> 3, mb = o & 7;
    const int m0 = mb * 64, n0 = nb * 128;

    f32x4 acc[4][2] = {};
    gemm64x128(x16, Wt, NQKV, m0, n0, lds, acc);

    const int tid = threadIdx.x;
    const int lane = tid & 63;
    const int quad = lane >> 4, l16 = lane & 15;
    const int wn = (tid >> 6) * 32;

    if (n0 < 5120) {
        // Q or K tile: bias + RoPE (adjacent-lane pairs) + fp16 store
        const bool isQ = n0 < 4096;
        const float* bias = isQ ? bq : bk;
        const int bOff = isQ ? 0 : 4096;
        half_t* dst = isQ ? q16 : k16;
        const int ldd = isQ ? 4096 : 1024;
#pragma unroll
        for (int i = 0; i < 4; ++i)
#pragma unroll
            for (int j = 0; j < 2; ++j) {
                const int col = n0 + wn + j * 16 + l16;   // even iff l16 even
                const int d2 = (col >> 1) & 63;
                const float bcol = bias[col - bOff];
#pragma unroll
                for (int rg = 0; rg < 4; ++rg) {
                    const int row = m0 + i * 16 + quad * 4 + rg;
                    float v = acc[i][j][rg] + bcol;
                    float p = __shfl_xor(v, 1);           // (re,im) partner
                    const int iloc = row & 127;
                    const float c = fc[iloc * 64 + d2], sn = fs[iloc * 64 + d2];
                    float ov = (l16 & 1) ? (p * sn + v * c)   // im' = re*s + im*c
                                         : (v * c - p * sn);  // re' = re*c - im*s
                    float o2 = __shfl_xor(ov, 1);
                    if (!(l16 & 1)) {
                        __align__(4) half_t hh[2] = {(half_t)ov, (half_t)o2};
                        *(unsigned int*)&dst[(size_t)row * ldd + (col - bOff)] =
                            *(unsigned int*)hh;
                    }
                }
            }
    } else {
        // V tile: bias -> LDS fp16 -> transposed coalesced store to vt16[d][i]
        half_t (*Th)[136] = (half_t(*)[136])lds;   // 64 x 136 x 2 = 17408 B
#pragma unroll
        for (int i = 0; i < 4; ++i)
#pragma unroll
            for (int j = 0; j < 2; ++j) {
                const int cl = wn + j * 16 + l16;
                const float bcol = bv[n0 - 5120 + cl];
#pragma unroll
                for (int rg = 0; rg < 4; ++rg)
                    Th[i * 16 + quad * 4 + rg][cl] = (half_t)(acc[i][j][rg] + bcol);
            }
        __syncthreads();
        const int d = tid >> 1, ih = tid & 1;     // 128 d x 2 i-halves of 32
        const int kv = (n0 - 5120) >> 7;
        const int b = mb >> 1, i0 = (mb & 1) * 64;
        __align__(16) half_t hs[32];
#pragma unroll
        for (int u = 0; u < 32; ++u) hs[u] = Th[ih * 32 + u][d];
        size_t base = ((size_t)(b * 8 + kv) * 128 + d) * 128 + i0 + ih * 32;
#pragma unroll
        for (int u = 0; u < 4; ++u)
            *(uint4*)&vt16[base + u * 8] = *(uint4*)&hs[u * 8];
    }
}

// ---------------------------------------------------------------------------
// Packed: fused attention (512 blocks) + wo transpose (2048 blocks).
// wo-T output WtO aliases Wt (safe: Wt last read in previous launch).
__global__ __launch_bounds__(256, 2)
void attn_wo(const half_t* __restrict__ q16, const half_t* __restrict__ k16,
             const half_t* __restrict__ vt16, half_t* __restrict__ a16,
             const float* __restrict__ wo, half_t* __restrict__ WtO) {
    __shared__ __align__(16) char lds[62464];
    if (blockIdx.x >= 512) {
        int t = blockIdx.x - 512;
        transpose_tile(wo, 4096, (t & 31) * 128, (t & 31) * 128, (t >> 5) * 64,
                       4096, WtO, lds);
        return;
    }
    half_t (*Qs)[136] = (half_t(*)[136])lds;            //  8704 B
    half_t (*Ks)[136] = (half_t(*)[136])(lds + 8704);   // 34816 B
    float (*Ps)[132]  = (float(*)[132])(lds + 43520);   // 16896 B
    float (*red)[16]  = (float(*)[16])(lds + 60416);    //  2048 B

    const int tid = threadIdx.x;
    const int qi = blockIdx.x & 3, h = (blockIdx.x >> 2) & 31, b = blockIdx.x >> 7;
    const int kv = h >> 2;
    const int qbase = qi * 32;
    const int lane = tid & 63, w = tid >> 6;
    const int quad = lane >> 4, l16 = lane & 15;
    const int m0 = (w & 1) * 16, half64 = (w >> 1) * 64;

#pragma unroll
    for (int p = 0; p < 2; ++p) {
        int task = tid + p * 256;
        int r = task >> 4, c = task & 15;
        *(uint4*)&Qs[r][c * 8] =
            *(const uint4*)&q16[((size_t)(b * 128 + qbase + r) * 32 + h) * 128 + c * 8];
    }
#pragma unroll
    for (int p = 0; p < 8; ++p) {
        int task = tid + p * 256;
        int r = task >> 4, c = task & 15;
        *(uint4*)&Ks[r][c * 8] =
            *(const uint4*)&k16[((size_t)(b * 128 + r) * 8 + kv) * 128 + c * 8];
    }
    __syncthreads();

    // phase 1: S = Q K^T
    f32x4 s[4] = {};
#pragma unroll
    for (int kc = 0; kc < 4; ++kc) {
        f16x8 af = *(const f16x8*)&Qs[m0 + l16][kc * 32 + quad * 8];
#pragma unroll
        for (int jb = 0; jb < 4; ++jb) {
            f16x8 bf = *(const f16x8*)&Ks[half64 + jb * 16 + l16][kc * 32 + quad * 8];
            s[jb] = __builtin_amdgcn_mfma_f32_16x16x32_f16(af, bf, s[jb], 0, 0, 0);
        }
    }
#pragma unroll
    for (int jb = 0; jb < 4; ++jb) {
        int j = half64 + jb * 16 + l16;
#pragma unroll
        for (int rg = 0; rg < 4; ++rg) {
            int row = m0 + quad * 4 + rg;
            Ps[row][j] = (j <= qbase + row) ? s[jb][rg] * SCALE_ : -1e30f;
        }
    }
    __syncthreads();

    // softmax: thread t -> row r, 16-col segment seg
    const int r = tid >> 3, seg = tid & 7;
    float mx = -1e30f;
#pragma unroll
    for (int i = 0; i < 16; ++i) mx = fmaxf(mx, Ps[r][seg * 16 + i]);
    red[r][seg] = mx;
    __syncthreads();

    uint4 vstage[8];
#pragma unroll
    for (int p = 0; p < 8; ++p) {
        int task = tid + p * 256;
        int rr = task >> 4, c = task & 15;
        vstage[p] = *(const uint4*)&vt16[((size_t)(b * 8 + kv) * 128 + rr) * 128 + c * 8];
    }
    float m = red[r][0];
#pragma unroll
    for (int i = 1; i < 8; ++i) m = fmaxf(m, red[r][i]);
    float sum = 0.f;
#pragma unroll
    for (int i = 0; i < 16; ++i) {
        float e = __expf(Ps[r][seg * 16 + i] - m);
        Ps[r][seg * 16 + i] = e;
        sum += e;
    }
    red[r][8 + seg] = sum;
#pragma unroll
    for (int p = 0; p < 8; ++p) {
        int task = tid + p * 256;
        int rr = task >> 4, c = task & 15;
        *(uint4*)&Ks[rr][c * 8] = vstage[p];   // Vt[d][j]
    }
    __syncthreads();

    float tot = 0.f;
#pragma unroll
    for (int i = 0; i < 8; ++i) tot += red[r][8 + i];
    float inv = 1.0f / tot;
#pragma unroll
    for (int i = 0; i < 16; ++i)
        Qs[r][seg * 16 + i] = (half_t)(Ps[r][seg * 16 + i] * inv);
    __syncthreads();

    // phase 2: O = P V
    f32x4 o[4] = {};
#pragma unroll
    for (int jc = 0; jc < 4; ++jc) {
        f16x8 af = *(const f16x8*)&Qs[m0 + l16][jc * 32 + quad * 8];
#pragma unroll
        for (int db = 0; db < 4; ++db) {
            f16x8 bf = *(const f16x8*)&Ks[half64 + db * 16 + l16][jc * 32 + quad * 8];
            o[db] = __builtin_amdgcn_mfma_f32_16x16x32_f16(af, bf, o[db], 0, 0, 0);
        }
    }
#pragma unroll
    for (int db = 0; db < 4; ++db) {
        int d = half64 + db * 16 + l16;
#pragma unroll
        for (int rg = 0; rg < 4; ++rg) {
            int row = m0 + quad * 4 + rg;
            a16[(size_t)(b * 128 + qbase + row) * 4096 + h * 128 + d] = (half_t)o[db][rg];
        }
    }
}

// ---------------------------------------------------------------------------
// O projection + fused +bo, fp32 store. Grid 256 = 8 m x 32 n, XCD-swizzled.
__global__ __launch_bounds__(256, 2)
void gemm_o_fused(const half_t* __restrict__ a16, const half_t* __restrict__ WtO,
                  const float* __restrict__ bo, float* __restrict__ out) {
    __shared__ __align__(16) char lds[49152];
    const int bx = blockIdx.x;
    const int o = (bx & 7) * 32 + (bx >> 3);  // bijective, 256 = 8 XCD x 32
    const int nb = o >> 3, mb = o & 7;
    const int m0 = mb * 64, n0 = nb * 128;

    f32x4 acc[4][2] = {};
    gemm64x128(a16, WtO, 4096, m0, n0, lds, acc);

    const int tid = threadIdx.x;
    const int lane = tid & 63;
    const int quad = lane >> 4, l16 = lane & 15;
    const int wn = (tid >> 6) * 32;
#pragma unroll
    for (int i = 0; i < 4; ++i)
#pragma unroll
        for (int j = 0; j < 2; ++j) {
            const int col = n0 + wn + j * 16 + l16;
            const float bcol = bo[col];
#pragma unroll
            for (int rg = 0; rg < 4; ++rg) {
                const int row = m0 + i * 16 + quad * 4 + rg;
                out[(size_t)row * 4096 + col] = acc[i][j][rg] + bcol;
            }
        }
}

// ---------------------------------------------------------------------------
extern "C" void kernel_launch(void* const* d_in, const int* in_sizes, int n_in,
                              void* d_out, int out_size, void* d_ws, size_t ws_size,
                              hipStream_t stream) {
    const float* x    = (const float*)d_in[0];
    const float* fc   = (const float*)d_in[2];
    const float* fs   = (const float*)d_in[3];
    const float* wq   = (const float*)d_in[7];
    const float* bq   = (const float*)d_in[8];
    const float* wk   = (const float*)d_in[9];
    const float* bk   = (const float*)d_in[10];
    const float* wv   = (const float*)d_in[11];
    const float* bv   = (const float*)d_in[12];
    const float* wo   = (const float*)d_in[13];
    const float* bo   = (const float*)d_in[14];
    float* out = (float*)d_out;

    half_t* x16  = (half_t*)d_ws;            //  2,097,152 h
    half_t* a16  = x16 + 2097152;            //  2,097,152 h
    half_t* q16  = a16 + 2097152;            //  2,097,152 h
    half_t* k16  = q16 + 2097152;            //    524,288 h
    half_t* vt16 = k16 + 524288;             //    524,288 h
    half_t* Wt   = vt16 + 524288;            // 25,165,824 h (ends @65,011,712 B)
    half_t* WtO  = Wt;                       // alias: wo-T runs after QKV gemm,
                                             // which is the last reader of Wt.

    // 1. QKV weight transpose + x convert
    prep_qkv<<<3584, 256, 0, stream>>>(wq, wk, wv, x, Wt, x16);

    // 2. QKV gemm, full-K, dbuf prefetch, fused bias+RoPE epilogue
    gemm_qkv_fused<<<384, 256, 0, stream>>>(x16, Wt, bq, bk, bv, fc, fs,
                                            q16, k16, vt16);

    // 3. fused attention + wo transpose packed into idle BW
    attn_wo<<<2560, 256, 0, stream>>>(q16, k16, vt16, a16, wo, WtO);

    // 4. O projection, full-K, dbuf prefetch, fused +bo
    gemm_o_fused<<<256, 256, 0, stream>>>(a16, WtO, bo, out);
}

// Round 3
// 283.105 us; speedup vs baseline: 1.1109x; 1.0650x over previous
//
#include <hip/hip_runtime.h>
#include <math.h>

// GroupedQueryAttention: B=4,S=128,D=4096,H=32,KV=8,HD=128,REP=4
// Round 9: counted-vmcnt deep pipeline (T3/T4) in the gemm core.
//   r8's loop was stage(t+1) -> compute(t) -> __syncthreads: the barrier
//   drains vmcnt(0), exposing the full prefetch latency every BK=64 step
//   (MfmaUtil 19%). Now: 3 LDS buffers, depth-2 prefetch, per-step
//   "s_waitcnt vmcnt(6)" + raw s_barrier (t+2's 6 loads stay in flight
//   across the barrier). sched_barrier(0) fences per methodology rule #18.

#define B_   4
#define S_   128
#define D_   4096
#define H_   32
#define KV_  8
#define HD_  128
#define M_   (B_ * S_)        // 512 rows
#define NQKV 6144
#define SCALE_ 0.088388347648318447f  // 1/sqrt(128)

typedef _Float16 half_t;
typedef half_t f16x8 __attribute__((ext_vector_type(8)));
typedef float  f32x4 __attribute__((ext_vector_type(4)));

__device__ inline void load_lds16(const void* g, void* l) {
    __builtin_amdgcn_global_load_lds((const __attribute__((address_space(1))) void*)g,
                                     (__attribute__((address_space(3))) void*)l,
                                     16, 0, 0);
}

// ---------------------------------------------------------------------------
// One 128n x 64k transpose tile: W[k0..+64][nsrc0..+128] fp32 ->
// Wt slab (k0/64): rows ndst0..+128 x 64 halfs  (16KB contiguous write).
// 256 threads.
__device__ void transpose_tile(const float* __restrict__ src, int Nsrc, int nsrc0,
                               int ndst0, int k0, int Ntot,
                               half_t* __restrict__ Wt, void* ldsraw) {
    float (*tile)[132] = (float(*)[132])ldsraw;   // [64k][128n], pad 132
    const int t = threadIdx.x;
#pragma unroll
    for (int p = 0; p < 8; ++p) {
        int idx = t + p * 256;              // 2048 float4 tasks
        int r = idx >> 5, c4 = idx & 31;    // 64 k-rows x 32 float4
        *(float4*)&tile[r][c4 * 4] =
            *(const float4*)&src[(size_t)(k0 + r) * Nsrc + nsrc0 + c4 * 4];
    }
    __syncthreads();
    const int n = t >> 1, kh = t & 1;       // 128 n-rows, 2 k-halves of 32
    __align__(16) half_t hs[32];
#pragma unroll
    for (int i = 0; i < 32; ++i)
        hs[i] = (half_t)tile[kh * 32 + i][n];
    size_t ob = ((size_t)(k0 >> 6) * Ntot + ndst0 + n) * 64 + kh * 32;
#pragma unroll
    for (int u = 0; u < 4; ++u)
        *(uint4*)&Wt[ob + u * 8] = *(uint4*)&hs[u * 8];
}

// ---------------------------------------------------------------------------
// Packed: QKV weight transpose (3072 blocks) + x fp32->fp16 (512 blocks).
__global__ __launch_bounds__(256)
void prep_qkv(const float* __restrict__ wq, const float* __restrict__ wk,
              const float* __restrict__ wv, const float* __restrict__ x,
              half_t* __restrict__ Wt, half_t* __restrict__ x16) {
    __shared__ __align__(16) char lds[33792];
    const int bx = blockIdx.x;
    if (bx < 3072) {
        int nt = bx % 48, kt = bx / 48;
        const float* src; int Nsrc, ns0, nd0;
        if (nt < 32)      { src = wq; Nsrc = 4096; ns0 = nt * 128;        nd0 = nt * 128; }
        else if (nt < 40) { src = wk; Nsrc = 1024; ns0 = (nt - 32) * 128; nd0 = 4096 + (nt - 32) * 128; }
        else              { src = wv; Nsrc = 1024; ns0 = (nt - 40) * 128; nd0 = 5120 + (nt - 40) * 128; }
        transpose_tile(src, Nsrc, ns0, nd0, kt * 64, NQKV, Wt, lds);
    } else {
        int i0 = (bx - 3072) * 1024 + threadIdx.x;
#pragma unroll
        for (int j = 0; j < 4; ++j) {
            int i = i0 + j * 256;
            float4 f = ((const float4*)x)[i];
            __align__(8) half_t h4[4] = {(half_t)f.x, (half_t)f.y, (half_t)f.z, (half_t)f.w};
            ((uint2*)x16)[i] = *(uint2*)h4;
        }
    }
}

// ---------------------------------------------------------------------------
// 64m x 128n full-K=4096 gemm core, 256 threads (4 waves, each 64m x 32n).
// 3 LDS buffers, depth-2 DMA prefetch, counted vmcnt(6) + raw s_barrier:
// tile t+2's 6 loads/wave stay in flight across the barrier ending step t.
__device__ __forceinline__ void stage64x128(const half_t* __restrict__ A,
                                            const half_t* __restrict__ Bbase,
                                            int N, int m0, int n0, int kc,
                                            half_t* AsD, half_t* BsD, int tid) {
    const int lane = tid & 63, tB = tid & 192;
    const half_t* Bslab = Bbase + ((size_t)(kc >> 6) * N + n0) * 64;
#pragma unroll
    for (int p = 0; p < 2; ++p) {           // A: 512 tasks (64 rows x 8 chunks)
        int tb = p * 256 + tB;
        int task = tb + lane;
        int r = task >> 3, os = (task ^ r) & 7;
        load_lds16(&A[(size_t)(m0 + r) * 4096 + kc + os * 8], AsD + tb * 8);
    }
#pragma unroll
    for (int p = 0; p < 4; ++p) {           // B: 1024 tasks (128 rows x 8 chunks)
        int tb = p * 256 + tB;
        int task = tb + lane;
        int r = task >> 3, os = (task ^ r) & 7;
        load_lds16(&Bslab[(size_t)r * 64 + os * 8], BsD + tb * 8);
    }
}

__device__ __forceinline__ void compute64x128(const half_t* AsD, const half_t* BsD,
                                              int tid, f32x4 (&acc)[4][2]) {
    const int lane = tid & 63;
    const int quad = lane >> 4, l16 = lane & 15;
    const int wn = (tid >> 6) * 32;
    half_t (*As)[64] = (half_t(*)[64])AsD;
    half_t (*Bs)[64] = (half_t(*)[64])BsD;
#pragma unroll
    for (int kk = 0; kk < 2; ++kk) {
        f16x8 af[4], bf[2];
        int L = kk * 4 + quad;
#pragma unroll
        for (int i = 0; i < 4; ++i) {
            int ra = i * 16 + l16;
            af[i] = *(const f16x8*)&As[ra][(L ^ (ra & 7)) * 8];
        }
#pragma unroll
        for (int j = 0; j < 2; ++j) {
            int rb = wn + j * 16 + l16;
            bf[j] = *(const f16x8*)&Bs[rb][(L ^ (rb & 7)) * 8];
        }
#pragma unroll
        for (int i = 0; i < 4; ++i)
#pragma unroll
            for (int j = 0; j < 2; ++j)
                acc[i][j] = __builtin_amdgcn_mfma_f32_16x16x32_f16(af[i], bf[j], acc[i][j], 0, 0, 0);
    }
}

__device__ __forceinline__ void fence_step(int n) {
    // wait until only n VMEM ops outstanding, then barrier WITHOUT draining
    if (n == 6)      asm volatile("s_waitcnt vmcnt(6)" ::: "memory");
    else if (n == 0) asm volatile("s_waitcnt vmcnt(0)" ::: "memory");
    __builtin_amdgcn_s_barrier();
    __builtin_amdgcn_sched_barrier(0);
}

__device__ __forceinline__ void gemm64x128(const half_t* __restrict__ A,
                                           const half_t* __restrict__ Bbase,
                                           int N, int m0, int n0, char* lds,
                                           f32x4 (&acc)[4][2]) {
    const int tid = threadIdx.x;
    half_t* As0 = (half_t*)lds;              // [3][64][64]   24KB
    half_t* Bs0 = (half_t*)(lds + 24576);    // [3][128][64]  48KB
    // prologue: tiles 0 and 1 in flight (12 loads/wave)
    stage64x128(A, Bbase, N, m0, n0, 0,  As0,        Bs0,        tid);
    stage64x128(A, Bbase, N, m0, n0, 64, As0 + 4096, Bs0 + 8192, tid);
    fence_step(6);                           // tile 0 landed; tile 1 in flight
    int cur = 0, pf = 2;
    for (int it = 0; it < 62; ++it) {
        stage64x128(A, Bbase, N, m0, n0, (it + 2) * 64,
                    As0 + pf * 4096, Bs0 + pf * 8192, tid);
        compute64x128(As0 + cur * 4096, Bs0 + cur * 8192, tid, acc);
        fence_step(6);                       // tile it+1 landed; it+2 in flight
        cur = (cur == 2) ? 0 : cur + 1;
        pf  = (pf  == 2) ? 0 : pf  + 1;
    }
    compute64x128(As0 + cur * 4096, Bs0 + cur * 8192, tid, acc);  // tile 62
    fence_step(0);                           // tile 63 landed
    cur = (cur == 2) ? 0 : cur + 1;
    compute64x128(As0 + cur * 4096, Bs0 + cur * 8192, tid, acc);  // tile 63
    __syncthreads();                         // LDS free for epilogue reuse
}

// ---------------------------------------------------------------------------
// QKV gemm + fused bias+RoPE+fp16 epilogue.
// Grid 384 = 8 m-tiles x 48 n-tiles, XCD-swizzled (same-n blocks -> same XCD).
__global__ __launch_bounds__(256, 2)
void gemm_qkv_fused(const half_t* __restrict__ x16, const half_t* __restrict__ Wt,
                    const float* __restrict__ bq, const float* __restrict__ bk,
                    const float* __restrict__ bv, const float* __restrict__ fc,
                    const float* __restrict__ fs, half_t* __restrict__ q16,
                    half_t* __restrict__ k16, half_t* __restrict__ vt16) {
    __shared__ __align__(16) char lds[73728];
    const int bx = blockIdx.x;
    const int o = (bx & 7) * 48 + (bx >> 3);  // bijective, 384 = 8 XCD x 48
    const int nb = o >> 3, mb = o & 7;
    const int m0 = mb * 64, n0 = nb * 128;

    f32x4 acc[4][2] = {};
    gemm64x128(x16, Wt, NQKV, m0, n0, lds, acc);

    const int tid = threadIdx.x;
    const int lane = tid & 63;
    const int quad = lane >> 4, l16 = lane & 15;
    const int wn = (tid >> 6) * 32;

    if (n0 < 5120) {
        // Q or K tile: bias + RoPE (adjacent-lane pairs) + fp16 store
        const bool isQ = n0 < 4096;
        const float* bias = isQ ? bq : bk;
        const int bOff = isQ ? 0 : 4096;
        half_t* dst = isQ ? q16 : k16;
        const int ldd = isQ ? 4096 : 1024;
#pragma unroll
        for (int i = 0; i < 4; ++i)
#pragma unroll
            for (int j = 0; j < 2; ++j) {
                const int col = n0 + wn + j * 16 + l16;   // even iff l16 even
                const int d2 = (col >> 1) & 63;
                const float bcol = bias[col - bOff];
#pragma unroll
                for (int rg = 0; rg < 4; ++rg) {
                    const int row = m0 + i * 16 + quad * 4 + rg;
                    float v = acc[i][j][rg] + bcol;
                    float p = __shfl_xor(v, 1);           // (re,im) partner
                    const int iloc = row & 127;
                    const float c = fc[iloc * 64 + d2], sn = fs[iloc * 64 + d2];
                    float ov = (l16 & 1) ? (p * sn + v * c)   // im' = re*s + im*c
                                         : (v * c - p * sn);  // re' = re*c - im*s
                    float o2 = __shfl_xor(ov, 1);
                    if (!(l16 & 1)) {
                        __align__(4) half_t hh[2] = {(half_t)ov, (half_t)o2};
                        *(unsigned int*)&dst[(size_t)row * ldd + (col - bOff)] =
                            *(unsigned int*)hh;
                    }
                }
            }
    } else {
        // V tile: bias -> LDS fp16 -> transposed coalesced store to vt16[d][i]
        half_t (*Th)[136] = (half_t(*)[136])lds;   // 64 x 136 x 2 = 17408 B
#pragma unroll
        for (int i = 0; i < 4; ++i)
#pragma unroll
            for (int j = 0; j < 2; ++j) {
                const int cl = wn + j * 16 + l16;
                const float bcol = bv[n0 - 5120 + cl];
#pragma unroll
                for (int rg = 0; rg < 4; ++rg)
                    Th[i * 16 + quad * 4 + rg][cl] = (half_t)(acc[i][j][rg] + bcol);
            }
        __syncthreads();
        const int d = tid >> 1, ih = tid & 1;     // 128 d x 2 i-halves of 32
        const int kv = (n0 - 5120) >> 7;
        const int b = mb >> 1, i0 = (mb & 1) * 64;
        __align__(16) half_t hs[32];
#pragma unroll
        for (int u = 0; u < 32; ++u) hs[u] = Th[ih * 32 + u][d];
        size_t base = ((size_t)(b * 8 + kv) * 128 + d) * 128 + i0 + ih * 32;
#pragma unroll
        for (int u = 0; u < 4; ++u)
            *(uint4*)&vt16[base + u * 8] = *(uint4*)&hs[u * 8];
    }
}

// ---------------------------------------------------------------------------
// Packed: fused attention (512 blocks) + wo transpose (2048 blocks).
// wo-T output WtO aliases Wt (safe: Wt last read in previous launch).
__global__ __launch_bounds__(256, 2)
void attn_wo(const half_t* __restrict__ q16, const half_t* __restrict__ k16,
             const half_t* __restrict__ vt16, half_t* __restrict__ a16,
             const float* __restrict__ wo, half_t* __restrict__ WtO) {
    __shared__ __align__(16) char lds[62464];
    if (blockIdx.x >= 512) {
        int t = blockIdx.x - 512;
        transpose_tile(wo, 4096, (t & 31) * 128, (t & 31) * 128, (t >> 5) * 64,
                       4096, WtO, lds);
        return;
    }
    half_t (*Qs)[136] = (half_t(*)[136])lds;            //  8704 B
    half_t (*Ks)[136] = (half_t(*)[136])(lds + 8704);   // 34816 B
    float (*Ps)[132]  = (float(*)[132])(lds + 43520);   // 16896 B
    float (*red)[16]  = (float(*)[16])(lds + 60416);    //  2048 B

    const int tid = threadIdx.x;
    const int qi = blockIdx.x & 3, h = (blockIdx.x >> 2) & 31, b = blockIdx.x >> 7;
    const int kv = h >> 2;
    const int qbase = qi * 32;
    const int lane = tid & 63, w = tid >> 6;
    const int quad = lane >> 4, l16 = lane & 15;
    const int m0 = (w & 1) * 16, half64 = (w >> 1) * 64;

#pragma unroll
    for (int p = 0; p < 2; ++p) {
        int task = tid + p * 256;
        int r = task >> 4, c = task & 15;
        *(uint4*)&Qs[r][c * 8] =
            *(const uint4*)&q16[((size_t)(b * 128 + qbase + r) * 32 + h) * 128 + c * 8];
    }
#pragma unroll
    for (int p = 0; p < 8; ++p) {
        int task = tid + p * 256;
        int r = task >> 4, c = task & 15;
        *(uint4*)&Ks[r][c * 8] =
            *(const uint4*)&k16[((size_t)(b * 128 + r) * 8 + kv) * 128 + c * 8];
    }
    __syncthreads();

    // phase 1: S = Q K^T
    f32x4 s[4] = {};
#pragma unroll
    for (int kc = 0; kc < 4; ++kc) {
        f16x8 af = *(const f16x8*)&Qs[m0 + l16][kc * 32 + quad * 8];
#pragma unroll
        for (int jb = 0; jb < 4; ++jb) {
            f16x8 bf = *(const f16x8*)&Ks[half64 + jb * 16 + l16][kc * 32 + quad * 8];
            s[jb] = __builtin_amdgcn_mfma_f32_16x16x32_f16(af, bf, s[jb], 0, 0, 0);
        }
    }
#pragma unroll
    for (int jb = 0; jb < 4; ++jb) {
        int j = half64 + jb * 16 + l16;
#pragma unroll
        for (int rg = 0; rg < 4; ++rg) {
            int row = m0 + quad * 4 + rg;
            Ps[row][j] = (j <= qbase + row) ? s[jb][rg] * SCALE_ : -1e30f;
        }
    }
    __syncthreads();

    // softmax: thread t -> row r, 16-col segment seg
    const int r = tid >> 3, seg = tid & 7;
    float mx = -1e30f;
#pragma unroll
    for (int i = 0; i < 16; ++i) mx = fmaxf(mx, Ps[r][seg * 16 + i]);
    red[r][seg] = mx;
    __syncthreads();

    uint4 vstage[8];
#pragma unroll
    for (int p = 0; p < 8; ++p) {
        int task = tid + p * 256;
        int rr = task >> 4, c = task & 15;
        vstage[p] = *(const uint4*)&vt16[((size_t)(b * 8 + kv) * 128 + rr) * 128 + c * 8];
    }
    float m = red[r][0];
#pragma unroll
    for (int i = 1; i < 8; ++i) m = fmaxf(m, red[r][i]);
    float sum = 0.f;
#pragma unroll
    for (int i = 0; i < 16; ++i) {
        float e = __expf(Ps[r][seg * 16 + i] - m);
        Ps[r][seg * 16 + i] = e;
        sum += e;
    }
    red[r][8 + seg] = sum;
#pragma unroll
    for (int p = 0; p < 8; ++p) {
        int task = tid + p * 256;
        int rr = task >> 4, c = task & 15;
        *(uint4*)&Ks[rr][c * 8] = vstage[p];   // Vt[d][j]
    }
    __syncthreads();

    float tot = 0.f;
#pragma unroll
    for (int i = 0; i < 8; ++i) tot += red[r][8 + i];
    float inv = 1.0f / tot;
#pragma unroll
    for (int i = 0; i < 16; ++i)
        Qs[r][seg * 16 + i] = (half_t)(Ps[r][seg * 16 + i] * inv);
    __syncthreads();

    // phase 2: O = P V
    f32x4 o[4] = {};
#pragma unroll
    for (int jc = 0; jc < 4; ++jc) {
        f16x8 af = *(const f16x8*)&Qs[m0 + l16][jc * 32 + quad * 8];
#pragma unroll
        for (int db = 0; db < 4; ++db) {
            f16x8 bf = *(const f16x8*)&Ks[half64 + db * 16 + l16][jc * 32 + quad * 8];
            o[db] = __builtin_amdgcn_mfma_f32_16x16x32_f16(af, bf, o[db], 0, 0, 0);
        }
    }
#pragma unroll
    for (int db = 0; db < 4; ++db) {
        int d = half64 + db * 16 + l16;
#pragma unroll
        for (int rg = 0; rg < 4; ++rg) {
            int row = m0 + quad * 4 + rg;
            a16[(size_t)(b * 128 + qbase + row) * 4096 + h * 128 + d] = (half_t)o[db][rg];
        }
    }
}

// ---------------------------------------------------------------------------
// O projection + fused +bo, fp32 store. Grid 256 = 8 m x 32 n, XCD-swizzled.
__global__ __launch_bounds__(256, 2)
void gemm_o_fused(const half_t* __restrict__ a16, const half_t* __restrict__ WtO,
                  const float* __restrict__ bo, float* __restrict__ out) {
    __shared__ __align__(16) char lds[73728];
    const int bx = blockIdx.x;
    const int o = (bx & 7) * 32 + (bx >> 3);  // bijective, 256 = 8 XCD x 32
    const int nb = o >> 3, mb = o & 7;
    const int m0 = mb * 64, n0 = nb * 128;

    f32x4 acc[4][2] = {};
    gemm64x128(a16, WtO, 4096, m0, n0, lds, acc);

    const int tid = threadIdx.x;
    const int lane = tid & 63;
    const int quad = lane >> 4, l16 = lane & 15;
    const int wn = (tid >> 6) * 32;
#pragma unroll
    for (int i = 0; i < 4; ++i)
#pragma unroll
        for (int j = 0; j < 2; ++j) {
            const int col = n0 + wn + j * 16 + l16;
            const float bcol = bo[col];
#pragma unroll
            for (int rg = 0; rg < 4; ++rg) {
                const int row = m0 + i * 16 + quad * 4 + rg;
                out[(size_t)row * 4096 + col] = acc[i][j][rg] + bcol;
            }
        }
}

// ---------------------------------------------------------------------------
extern "C" void kernel_launch(void* const* d_in, const int* in_sizes, int n_in,
                              void* d_out, int out_size, void* d_ws, size_t ws_size,
                              hipStream_t stream) {
    const float* x    = (const float*)d_in[0];
    const float* fc   = (const float*)d_in[2];
    const float* fs   = (const float*)d_in[3];
    const float* wq   = (const float*)d_in[7];
    const float* bq   = (const float*)d_in[8];
    const float* wk   = (const float*)d_in[9];
    const float* bk   = (const float*)d_in[10];
    const float* wv   = (const float*)d_in[11];
    const float* bv   = (const float*)d_in[12];
    const float* wo   = (const float*)d_in[13];
    const float* bo   = (const float*)d_in[14];
    float* out = (float*)d_out;

    half_t* x16  = (half_t*)d_ws;            //  2,097,152 h
    half_t* a16  = x16 + 2097152;            //  2,097,152 h
    half_t* q16  = a16 + 2097152;            //  2,097,152 h
    half_t* k16  = q16 + 2097152;            //    524,288 h
    half_t* vt16 = k16 + 524288;             //    524,288 h
    half_t* Wt   = vt16 + 524288;            // 25,165,824 h (ends @65,011,712 B)
    half_t* WtO  = Wt;                       // alias: wo-T runs after QKV gemm,
                                             // which is the last reader of Wt.

    // 1. QKV weight transpose + x convert
    prep_qkv<<<3584, 256, 0, stream>>>(wq, wk, wv, x, Wt, x16);

    // 2. QKV gemm, full-K, depth-2 counted-vmcnt pipeline, fused epilogue
    gemm_qkv_fused<<<384, 256, 0, stream>>>(x16, Wt, bq, bk, bv, fc, fs,
                                            q16, k16, vt16);

    // 3. fused attention + wo transpose packed into idle BW
    attn_wo<<<2560, 256, 0, stream>>>(q16, k16, vt16, a16, wo, WtO);

    // 4. O projection, full-K, depth-2 counted-vmcnt pipeline, fused +bo
    gemm_o_fused<<<256, 256, 0, stream>>>(a16, WtO, bo, out);
}